// Round 1
// baseline (1139.961 us; speedup 1.0000x reference)
//
#include <hip/hip_runtime.h>
#include <math.h>

#define B 4
#define S 2048
#define D 1024
#define H 16
#define DK 64
#define MS (B * S)  // 8192

// ---------------------------------------------------------------------------
// Generic fp32 GEMM: C[M x N] = A[M x K] @ B + bias
// MODE 0 (projection): B(d, j) = W[(j>>6)*K*64 + d*64 + (j&63)]   (W is [H,D,DK])
// MODE 1 (output):     B(i, o) = W[o*K + i]                        (W is [D,D], used transposed)
// bias is [N] in both modes (wq_b flat [H*DK] matches col index h*64+k).
// Tile 128x128, BK=8, 256 threads, 8x8 per thread. All dims divide evenly.
// ---------------------------------------------------------------------------
template <int MODE>
__global__ __launch_bounds__(256) void sgemm_kernel(
    const float* __restrict__ A, const float* __restrict__ Wm,
    const float* __restrict__ bias, float* __restrict__ C, int M, int N, int K) {
  __shared__ float As[8][128];
  __shared__ float Bs[8][128];
  const int tid = threadIdx.x;
  const int bn = blockIdx.x * 128;
  const int bm = blockIdx.y * 128;
  const int tx = tid & 15;   // n direction
  const int ty = tid >> 4;   // m direction

  float acc[8][8];
#pragma unroll
  for (int i = 0; i < 8; i++)
#pragma unroll
    for (int j = 0; j < 8; j++) acc[i][j] = 0.f;

  const int arow = tid >> 1;        // 0..127
  const int akof = (tid & 1) * 4;   // 0 or 4

  for (int k0 = 0; k0 < K; k0 += 8) {
    // global loads into registers (overlap with previous tile's compute)
    float4 a4 = *(const float4*)&A[(size_t)(bm + arow) * K + k0 + akof];
    float4 b4;
    int jof = 0, dof = 0, oof = 0, iof = 0;
    if (MODE == 0) {
      jof = (tid & 31) * 4;  // 0..124, stays within a 64-wide head (multiple of 4)
      dof = tid >> 5;        // 0..7
      int j = bn + jof;
      int head = j >> 6;
      b4 = *(const float4*)&Wm[(size_t)head * (K * 64) + (size_t)(k0 + dof) * 64 + (j & 63)];
    } else {
      oof = tid >> 1;        // 0..127
      iof = (tid & 1) * 4;   // 0 or 4
      b4 = *(const float4*)&Wm[(size_t)(bn + oof) * K + k0 + iof];
    }
    __syncthreads();  // protect previous iteration's LDS reads
    As[akof + 0][arow] = a4.x;
    As[akof + 1][arow] = a4.y;
    As[akof + 2][arow] = a4.z;
    As[akof + 3][arow] = a4.w;
    if (MODE == 0) {
      *(float4*)&Bs[dof][jof] = b4;
    } else {
      Bs[iof + 0][oof] = b4.x;
      Bs[iof + 1][oof] = b4.y;
      Bs[iof + 2][oof] = b4.z;
      Bs[iof + 3][oof] = b4.w;
    }
    __syncthreads();
#pragma unroll
    for (int kk = 0; kk < 8; kk++) {
      float a[8], b[8];
      *(float4*)&a[0] = *(const float4*)&As[kk][ty * 8];
      *(float4*)&a[4] = *(const float4*)&As[kk][ty * 8 + 4];
      *(float4*)&b[0] = *(const float4*)&Bs[kk][tx * 8];
      *(float4*)&b[4] = *(const float4*)&Bs[kk][tx * 8 + 4];
#pragma unroll
      for (int i = 0; i < 8; i++)
#pragma unroll
        for (int j = 0; j < 8; j++) acc[i][j] += a[i] * b[j];
    }
  }

#pragma unroll
  for (int i = 0; i < 8; i++) {
    int row = bm + ty * 8 + i;
#pragma unroll
    for (int jc = 0; jc < 2; jc++) {
      int col = bn + tx * 8 + jc * 4;
      float4 o;
      o.x = acc[i][jc * 4 + 0] + bias[col + 0];
      o.y = acc[i][jc * 4 + 1] + bias[col + 1];
      o.z = acc[i][jc * 4 + 2] + bias[col + 2];
      o.w = acc[i][jc * 4 + 3] + bias[col + 3];
      *(float4*)&C[(size_t)row * N + col] = o;
    }
  }
}

// ---------------------------------------------------------------------------
// M[b,h] = kh[b,:,h,:]^T @ vh[b,:,h,:]  (64x64 per (b,h)), s-split with atomics.
// KH/VH layout: [B*S, 1024] with col = h*64+k. grid (8, H, B), 256 threads.
// ---------------------------------------------------------------------------
__global__ __launch_bounds__(256) void compute_m_kernel(
    const float* __restrict__ KH, const float* __restrict__ VH, float* __restrict__ Mout) {
  const int sc = blockIdx.x, h = blockIdx.y, b = blockIdx.z;
  const int tid = threadIdx.x;
  const int i0 = (tid >> 4) * 4;  // 0..60
  const int j0 = (tid & 15) * 4;  // 0..60
  __shared__ float ks[8][64], vs[8][64];
  float acc[4][4];
#pragma unroll
  for (int a = 0; a < 4; a++)
#pragma unroll
    for (int c = 0; c < 4; c++) acc[a][c] = 0.f;

  const int s0 = sc * (S / 8);  // 256 rows per block
  const int rr = tid >> 5;         // 0..7
  const int cc = (tid & 31) * 2;   // 0..62
  for (int s = s0; s < s0 + S / 8; s += 8) {
    size_t base = ((size_t)b * S + s + rr) * D + h * 64 + cc;
    __syncthreads();
    *(float2*)&ks[rr][cc] = *(const float2*)&KH[base];
    *(float2*)&vs[rr][cc] = *(const float2*)&VH[base];
    __syncthreads();
#pragma unroll
    for (int ss = 0; ss < 8; ss++) {
      float4 kf = *(const float4*)&ks[ss][i0];
      float4 vf = *(const float4*)&vs[ss][j0];
      float ka[4] = {kf.x, kf.y, kf.z, kf.w};
      float va[4] = {vf.x, vf.y, vf.z, vf.w};
#pragma unroll
      for (int a = 0; a < 4; a++)
#pragma unroll
        for (int c = 0; c < 4; c++) acc[a][c] += ka[a] * va[c];
    }
  }
  float* Mp = Mout + ((size_t)(b * H + h)) * DK * DK;
#pragma unroll
  for (int a = 0; a < 4; a++)
#pragma unroll
    for (int c = 0; c < 4; c++) atomicAdd(&Mp[(i0 + a) * DK + j0 + c], acc[a][c]);
}

// ---------------------------------------------------------------------------
// heads[b,s,h*64+j] = softmax_j( scale * qh[b,s,h,:] @ M[b,h][:,j] )
// In-place: HEADS may alias QH (each row is fully read before written, within
// one wave). grid (S/128, H, B), 256 threads; each wave owns 32 rows.
// ---------------------------------------------------------------------------
__global__ __launch_bounds__(256) void qm_softmax_kernel(
    const float* __restrict__ QH, const float* __restrict__ Mmat, float* __restrict__ HEADS) {
  const int sc = blockIdx.x, h = blockIdx.y, b = blockIdx.z;
  const int tid = threadIdx.x;
  const int lane = tid & 63;
  const int wv = tid >> 6;  // wave 0..3
  __shared__ float Ml[64][64];
  {
    const float* Mp = Mmat + ((size_t)(b * H + h)) * 4096;
    float* Mf = &Ml[0][0];
    for (int idx = tid * 4; idx < 4096; idx += 1024) *(float4*)&Mf[idx] = *(const float4*)&Mp[idx];
  }
  __syncthreads();

  const int srow_base = sc * 128 + wv * 32;
  for (int r = 0; r < 32; r++) {
    size_t rowoff = ((size_t)b * S + srow_base + r) * D + h * 64;
    float qv = QH[rowoff + lane];
    float accv = 0.f;
#pragma unroll
    for (int i = 0; i < 64; i++) {
      float qi = __shfl(qv, i, 64);
      accv += qi * Ml[i][lane];
    }
    accv *= 0.125f;  // 1/sqrt(DK)
    // 64-lane softmax
    float mx = accv;
#pragma unroll
    for (int off = 32; off > 0; off >>= 1) mx = fmaxf(mx, __shfl_xor(mx, off, 64));
    float e = __expf(accv - mx);
    float sm = e;
#pragma unroll
    for (int off = 32; off > 0; off >>= 1) sm += __shfl_xor(sm, off, 64);
    HEADS[rowoff + lane] = e / sm;
  }
}

// ---------------------------------------------------------------------------
extern "C" void kernel_launch(void* const* d_in, const int* in_sizes, int n_in,
                              void* d_out, int out_size, void* d_ws, size_t ws_size,
                              hipStream_t stream) {
  const float* q = (const float*)d_in[0];
  const float* k = (const float*)d_in[1];
  const float* v = (const float*)d_in[2];
  const float* wq_w = (const float*)d_in[3];
  const float* wq_b = (const float*)d_in[4];
  const float* wk_w = (const float*)d_in[5];
  const float* wk_b = (const float*)d_in[6];
  const float* wv_w = (const float*)d_in[7];
  const float* wv_b = (const float*)d_in[8];
  const float* wo_w = (const float*)d_in[9];
  const float* wo_b = (const float*)d_in[10];
  float* out = (float*)d_out;

  // workspace layout (bytes): KH 32MB | VH 32MB | QH/heads 32MB | M 1MB  = 97MB
  const size_t nProj = (size_t)MS * D;  // 8388608 floats
  float* KH = (float*)d_ws;
  float* VH = KH + nProj;
  float* QH = VH + nProj;  // reused in-place as heads
  float* M = QH + nProj;   // B*H*64*64 = 262144 floats

  dim3 gemmGrid(D / 128, MS / 128);  // (8, 64)
  dim3 blk(256);

  // k and v projections
  sgemm_kernel<0><<<gemmGrid, blk, 0, stream>>>(k, wk_w, wk_b, KH, MS, D, D);
  sgemm_kernel<0><<<gemmGrid, blk, 0, stream>>>(v, wv_w, wv_b, VH, MS, D, D);
  // q projection
  sgemm_kernel<0><<<gemmGrid, blk, 0, stream>>>(q, wq_w, wq_b, QH, MS, D, D);

  // M = kh^T vh per (b,h)
  hipMemsetAsync(M, 0, (size_t)B * H * DK * DK * sizeof(float), stream);
  compute_m_kernel<<<dim3(8, H, B), blk, 0, stream>>>(KH, VH, M);

  // out_pre = scale * qh @ M, then softmax over dk=64, in-place -> heads
  qm_softmax_kernel<<<dim3(S / 128, H, B), blk, 0, stream>>>(QH, M, QH);

  // final: heads @ wo_w^T + wo_b
  sgemm_kernel<1><<<gemmGrid, blk, 0, stream>>>(QH, wo_w, wo_b, out, MS, D, D);
}

// Round 3
// 636.639 us; speedup vs baseline: 1.7906x; 1.7906x over previous
//
#include <hip/hip_runtime.h>
#include <math.h>

#define B 4
#define S 2048
#define D 1024
#define H 16
#define DK 64
#define MS (B * S)   // 8192
#define GKA 2048     // A storage width: [hi | lo]
#define GKB 3072     // B storage width + logical K: [hi | hi | lo]

typedef short bf16x8 __attribute__((ext_vector_type(8)));
typedef float f32x4 __attribute__((ext_vector_type(4)));

__device__ __forceinline__ unsigned short f2bf(float x) {
  union { float f; unsigned u; } v; v.f = x;
  unsigned r = v.u + 0x7fff + ((v.u >> 16) & 1);  // RNE
  return (unsigned short)(r >> 16);
}
__device__ __forceinline__ float bf2f(unsigned short h) {
  union { unsigned u; float f; } v; v.u = ((unsigned)h) << 16;
  return v.f;
}
__device__ __forceinline__ void split2(float x, unsigned short& hi, unsigned short& lo) {
  hi = f2bf(x);
  lo = f2bf(x - bf2f(hi));
}

// ---------------------------------------------------------------------------
// split_a: X fp32 [8192][1024] -> O bf16 [8192][2048] ([hi | lo])
// ---------------------------------------------------------------------------
__global__ __launch_bounds__(256) void split_a_kernel(const float* __restrict__ X,
                                                      unsigned short* __restrict__ O) {
  int t = blockIdx.x * 256 + threadIdx.x;
  int idx = t * 4;
  int m = idx >> 10, d = idx & 1023;
  float4 x = *(const float4*)&X[idx];
  union { unsigned short h[4]; ushort4 u; } uh, ul;
  split2(x.x, uh.h[0], ul.h[0]);
  split2(x.y, uh.h[1], ul.h[1]);
  split2(x.z, uh.h[2], ul.h[2]);
  split2(x.w, uh.h[3], ul.h[3]);
  *(ushort4*)&O[(size_t)m * GKA + d] = uh.u;
  *(ushort4*)&O[(size_t)m * GKA + 1024 + d] = ul.u;
}

// ---------------------------------------------------------------------------
// split_wp: W fp32 [H][1024][64] -> O bf16 [1024][3072] ([hi | hi | lo]),
// row n = h*64+dk
// ---------------------------------------------------------------------------
__global__ __launch_bounds__(256) void split_wp_kernel(const float* __restrict__ W,
                                                       unsigned short* __restrict__ O) {
  int t = blockIdx.x * 256 + threadIdx.x;  // 1M threads
  int d = t & 1023, n = t >> 10;
  int h = n >> 6, dk = n & 63;
  float x = W[((size_t)(h << 10) + d) * 64 + dk];
  unsigned short hi, lo;
  split2(x, hi, lo);
  size_t ro = (size_t)n * GKB + d;
  O[ro] = hi;
  O[ro + 1024] = hi;
  O[ro + 2048] = lo;
}

// ---------------------------------------------------------------------------
// split_wo: W fp32 [1024][1024] (row=out, col=in; already B^T) -> [1024][3072]
// ---------------------------------------------------------------------------
__global__ __launch_bounds__(256) void split_wo_kernel(const float* __restrict__ W,
                                                       unsigned short* __restrict__ O) {
  int t = blockIdx.x * 256 + threadIdx.x;  // 256K threads, 4 elems each
  int idx = t * 4;
  int n = idx >> 10, d = idx & 1023;
  float4 x = *(const float4*)&W[idx];
  union { unsigned short h[4]; ushort4 u; } uh, ul;
  split2(x.x, uh.h[0], ul.h[0]);
  split2(x.y, uh.h[1], ul.h[1]);
  split2(x.z, uh.h[2], ul.h[2]);
  split2(x.w, uh.h[3], ul.h[3]);
  size_t ro = (size_t)n * GKB + d;
  *(ushort4*)&O[ro] = uh.u;
  *(ushort4*)&O[ro + 1024] = uh.u;
  *(ushort4*)&O[ro + 2048] = ul.u;
}

// ---------------------------------------------------------------------------
// gemm_bt_bf16: C[M x N] = A' @ BT'^T + bias over logical K=3072.
// A stored [M][2048]; k-block 2 re-reads hi (wrap addressing).
// BT stored [N][3072] = [hi | hi | lo].
// Computes hi*hi + lo*hi + hi*lo  (Markidis 3-term; only lo*lo dropped).
// OUT=0: fp32 C [M][N].  OUT=1: split bf16 C [M][2048] ([hi|lo]).
// 128x128 tile, BK=32, 4 waves, 16x16x32 MFMA, global_load_lds width 16.
// ---------------------------------------------------------------------------
#define BK 32
template <int OUT>
__global__ __launch_bounds__(256) void gemm_bt_bf16(
    const unsigned short* __restrict__ A, const unsigned short* __restrict__ BT,
    const float* __restrict__ bias, float* __restrict__ Cf,
    unsigned short* __restrict__ Cs, int N) {
  __shared__ __align__(16) unsigned short As[128 * BK];
  __shared__ __align__(16) unsigned short Bs[128 * BK];
  const int tid = threadIdx.x;
  const int lane = tid & 63;
  const int w = tid >> 6;
  const int wm = (w >> 1) * 64;
  const int wn = (w & 1) * 64;
  const size_t bm = (size_t)blockIdx.y * 128;
  const size_t bn = (size_t)blockIdx.x * 128;

  f32x4 acc[4][4];
#pragma unroll
  for (int i = 0; i < 4; i++)
#pragma unroll
    for (int j = 0; j < 4; j++) acc[i][j] = (f32x4){0.f, 0.f, 0.f, 0.f};

  const int srow = lane >> 2;       // 0..15
  const int skof = (lane & 3) * 8;  // k elem offset
  const unsigned short* Ag0 = A + (bm + w * 32 + srow) * GKA + skof;
  const unsigned short* Ag1 = Ag0 + (size_t)16 * GKA;
  const unsigned short* Bg0 = BT + (bn + w * 32 + srow) * GKB + skof;
  const unsigned short* Bg1 = Bg0 + (size_t)16 * GKB;
  unsigned short* As0 = As + (w * 2) * 512;
  unsigned short* As1 = As0 + 512;
  unsigned short* Bs0 = Bs + (w * 2) * 512;
  unsigned short* Bs1 = Bs0 + 512;

  const int fm = lane & 15;
  const int fk = (lane >> 4) * 8;

  for (int k0 = 0; k0 < GKB; k0 += BK) {
    const int ak = (k0 < 2048) ? k0 : (k0 - 2048);  // third block re-reads hi
    __syncthreads();
    __builtin_amdgcn_global_load_lds((const __attribute__((address_space(1))) void*)(Ag0 + ak),
                                     (__attribute__((address_space(3))) void*)As0, 16, 0, 0);
    __builtin_amdgcn_global_load_lds((const __attribute__((address_space(1))) void*)(Ag1 + ak),
                                     (__attribute__((address_space(3))) void*)As1, 16, 0, 0);
    __builtin_amdgcn_global_load_lds((const __attribute__((address_space(1))) void*)(Bg0 + k0),
                                     (__attribute__((address_space(3))) void*)Bs0, 16, 0, 0);
    __builtin_amdgcn_global_load_lds((const __attribute__((address_space(1))) void*)(Bg1 + k0),
                                     (__attribute__((address_space(3))) void*)Bs1, 16, 0, 0);
    __syncthreads();
    bf16x8 af[4], bf[4];
#pragma unroll
    for (int i = 0; i < 4; i++) {
      af[i] = *(const bf16x8*)&As[(wm + i * 16 + fm) * BK + fk];
      bf[i] = *(const bf16x8*)&Bs[(wn + i * 16 + fm) * BK + fk];
    }
#pragma unroll
    for (int i = 0; i < 4; i++)
#pragma unroll
      for (int j = 0; j < 4; j++)
        acc[i][j] = __builtin_amdgcn_mfma_f32_16x16x32_bf16(af[i], bf[j], acc[i][j], 0, 0, 0);
  }

  const int r0 = (lane >> 4) * 4;
#pragma unroll
  for (int i = 0; i < 4; i++)
#pragma unroll
    for (int j = 0; j < 4; j++) {
      size_t row = bm + wm + i * 16 + r0;
      size_t col = bn + wn + j * 16 + fm;
      float bb = bias[col];
#pragma unroll
      for (int r = 0; r < 4; r++) {
        float val = acc[i][j][r] + bb;
        if (OUT == 0) {
          Cf[(row + r) * N + col] = val;
        } else {
          unsigned short hi, lo;
          split2(val, hi, lo);
          Cs[(row + r) * GKA + col] = hi;
          Cs[(row + r) * GKA + 1024 + col] = lo;
        }
      }
    }
}

// ---------------------------------------------------------------------------
// M[b,h] = kh^T @ vh (64x64 per (b,h)), s-split 8-way with atomics.
// ---------------------------------------------------------------------------
__global__ __launch_bounds__(256) void compute_m_kernel(
    const float* __restrict__ KH, const float* __restrict__ VH, float* __restrict__ Mout) {
  const int sc = blockIdx.x, h = blockIdx.y, b = blockIdx.z;
  const int tid = threadIdx.x;
  const int i0 = (tid >> 4) * 4;
  const int j0 = (tid & 15) * 4;
  __shared__ float ks[16][64], vs[16][64];
  float acc[4][4];
#pragma unroll
  for (int a = 0; a < 4; a++)
#pragma unroll
    for (int c = 0; c < 4; c++) acc[a][c] = 0.f;

  const int s0 = sc * (S / 8);       // 256 rows per block
  const int rr = tid >> 4;           // 0..15
  const int cc = (tid & 15) * 4;     // 0..60
  for (int s = s0; s < s0 + S / 8; s += 16) {
    size_t base = ((size_t)b * S + s + rr) * D + h * 64 + cc;
    __syncthreads();
    *(float4*)&ks[rr][cc] = *(const float4*)&KH[base];
    *(float4*)&vs[rr][cc] = *(const float4*)&VH[base];
    __syncthreads();
#pragma unroll
    for (int ss = 0; ss < 16; ss++) {
      float4 kf = *(const float4*)&ks[ss][i0];
      float4 vf = *(const float4*)&vs[ss][j0];
      float ka[4] = {kf.x, kf.y, kf.z, kf.w};
      float va[4] = {vf.x, vf.y, vf.z, vf.w};
#pragma unroll
      for (int a = 0; a < 4; a++)
#pragma unroll
        for (int c = 0; c < 4; c++) acc[a][c] += ka[a] * va[c];
    }
  }
  float* Mp = Mout + ((size_t)(b * H + h)) * DK * DK;
#pragma unroll
  for (int a = 0; a < 4; a++)
#pragma unroll
    for (int c = 0; c < 4; c++) atomicAdd(&Mp[(i0 + a) * DK + j0 + c], acc[a][c]);
}

// ---------------------------------------------------------------------------
// heads = softmax_j( scale * qh @ M[b,h] ). QS is q-split [8192][2048] ([hi|lo]);
// output written IN-PLACE into QS as heads-split (same [hi|lo] columns).
// ---------------------------------------------------------------------------
__global__ __launch_bounds__(256) void qm_softmax_kernel(
    unsigned short* __restrict__ QS, const float* __restrict__ Mmat) {
  const int sc = blockIdx.x, h = blockIdx.y, b = blockIdx.z;
  const int tid = threadIdx.x;
  const int lane = tid & 63;
  const int wv = tid >> 6;
  __shared__ float Ml[64][64];
  {
    const float* Mp = Mmat + ((size_t)(b * H + h)) * 4096;
    float* Mf = &Ml[0][0];
    for (int idx = tid * 4; idx < 4096; idx += 1024) *(float4*)&Mf[idx] = *(const float4*)&Mp[idx];
  }
  __syncthreads();

  const int srow_base = sc * 128 + wv * 32;
  for (int r = 0; r < 32; r++) {
    size_t row = (size_t)b * S + srow_base + r;
    size_t ro = row * GKA + h * 64 + lane;
    float qv = bf2f(QS[ro]) + bf2f(QS[ro + 1024]);
    float accv = 0.f;
#pragma unroll
    for (int i = 0; i < 64; i++) {
      float qi = __shfl(qv, i, 64);
      accv += qi * Ml[i][lane];
    }
    accv *= 0.125f;
    float mx = accv;
#pragma unroll
    for (int off = 32; off > 0; off >>= 1) mx = fmaxf(mx, __shfl_xor(mx, off, 64));
    float e = __expf(accv - mx);
    float sm = e;
#pragma unroll
    for (int off = 32; off > 0; off >>= 1) sm += __shfl_xor(sm, off, 64);
    float p = e / sm;
    unsigned short hi, lo;
    split2(p, hi, lo);
    QS[ro] = hi;
    QS[ro + 1024] = lo;
  }
}

// ---------------------------------------------------------------------------
extern "C" void kernel_launch(void* const* d_in, const int* in_sizes, int n_in,
                              void* d_out, int out_size, void* d_ws, size_t ws_size,
                              hipStream_t stream) {
  const float* q = (const float*)d_in[0];
  const float* k = (const float*)d_in[1];
  const float* v = (const float*)d_in[2];
  const float* wq_w = (const float*)d_in[3];
  const float* wq_b = (const float*)d_in[4];
  const float* wk_w = (const float*)d_in[5];
  const float* wk_b = (const float*)d_in[6];
  const float* wv_w = (const float*)d_in[7];
  const float* wv_b = (const float*)d_in[8];
  const float* wo_w = (const float*)d_in[9];
  const float* wo_b = (const float*)d_in[10];
  float* out = (float*)d_out;

  // ws: KH 32MB (reused as QS after compute_m) | VH 32MB | M 1MB | ASP 32MB |
  //     WQS/WKS/WVS/WOS 6MB each = 121MB total
  const size_t nProj = (size_t)MS * D;  // 8M floats
  float* KH = (float*)d_ws;
  float* VH = KH + nProj;
  float* M = VH + nProj;                                    // 256K floats
  unsigned short* ASP = (unsigned short*)(M + 256 * 1024);  // [8192][2048]
  unsigned short* WQS = ASP + (size_t)MS * GKA;             // [1024][3072]
  unsigned short* WKS = WQS + (size_t)D * GKB;
  unsigned short* WVS = WKS + (size_t)D * GKB;
  unsigned short* WOS = WVS + (size_t)D * GKB;
  unsigned short* QS = (unsigned short*)KH;  // aliases KH after compute_m

  dim3 blk(256);
  dim3 gemmGrid(D / 128, MS / 128);  // (8, 64)

  split_wp_kernel<<<4096, blk, 0, stream>>>(wq_w, WQS);
  split_wp_kernel<<<4096, blk, 0, stream>>>(wk_w, WKS);
  split_wp_kernel<<<4096, blk, 0, stream>>>(wv_w, WVS);
  split_wo_kernel<<<1024, blk, 0, stream>>>(wo_w, WOS);
  hipMemsetAsync(M, 0, (size_t)B * H * DK * DK * sizeof(float), stream);

  split_a_kernel<<<8192, blk, 0, stream>>>(k, ASP);
  gemm_bt_bf16<0><<<gemmGrid, blk, 0, stream>>>(ASP, WKS, wk_b, KH, nullptr, D);
  split_a_kernel<<<8192, blk, 0, stream>>>(v, ASP);
  gemm_bt_bf16<0><<<gemmGrid, blk, 0, stream>>>(ASP, WVS, wv_b, VH, nullptr, D);

  compute_m_kernel<<<dim3(8, H, B), blk, 0, stream>>>(KH, VH, M);

  split_a_kernel<<<8192, blk, 0, stream>>>(q, ASP);
  gemm_bt_bf16<1><<<gemmGrid, blk, 0, stream>>>(ASP, WQS, wq_b, nullptr, QS, D);

  qm_softmax_kernel<<<dim3(S / 128, H, B), blk, 0, stream>>>(QS, M);

  gemm_bt_bf16<0><<<gemmGrid, blk, 0, stream>>>(QS, WOS, wo_b, out, nullptr, D);
}

// Round 4
// 547.559 us; speedup vs baseline: 2.0819x; 1.1627x over previous
//
#include <hip/hip_runtime.h>
#include <math.h>

#define B 4
#define S 2048
#define D 1024
#define H 16
#define DK 64
#define MS (B * S)   // 8192
#define GKA 2048     // A storage width: [hi | lo]
#define GKB 3072     // B storage width + logical K: [hi | hi | lo]

typedef short bf16x8 __attribute__((ext_vector_type(8)));
typedef float f32x4 __attribute__((ext_vector_type(4)));

__device__ __forceinline__ unsigned short f2bf(float x) {
  union { float f; unsigned u; } v; v.f = x;
  unsigned r = v.u + 0x7fff + ((v.u >> 16) & 1);  // RNE
  return (unsigned short)(r >> 16);
}
__device__ __forceinline__ float bf2f(unsigned short h) {
  union { unsigned u; float f; } v; v.u = ((unsigned)h) << 16;
  return v.f;
}
__device__ __forceinline__ void split2(float x, unsigned short& hi, unsigned short& lo) {
  hi = f2bf(x);
  lo = f2bf(x - bf2f(hi));
}

// ---------------------------------------------------------------------------
// split_a: X fp32 [8192][1024] -> O bf16 [8192][2048] ([hi | lo])
// ---------------------------------------------------------------------------
__global__ __launch_bounds__(256) void split_a_kernel(const float* __restrict__ X,
                                                      unsigned short* __restrict__ O) {
  int t = blockIdx.x * 256 + threadIdx.x;
  int idx = t * 4;
  int m = idx >> 10, d = idx & 1023;
  float4 x = *(const float4*)&X[idx];
  union { unsigned short h[4]; ushort4 u; } uh, ul;
  split2(x.x, uh.h[0], ul.h[0]);
  split2(x.y, uh.h[1], ul.h[1]);
  split2(x.z, uh.h[2], ul.h[2]);
  split2(x.w, uh.h[3], ul.h[3]);
  *(ushort4*)&O[(size_t)m * GKA + d] = uh.u;
  *(ushort4*)&O[(size_t)m * GKA + 1024 + d] = ul.u;
}

// ---------------------------------------------------------------------------
// split_wp: W fp32 [H][1024][64] -> O bf16 [1024][3072] ([hi | hi | lo])
// ---------------------------------------------------------------------------
__global__ __launch_bounds__(256) void split_wp_kernel(const float* __restrict__ W,
                                                       unsigned short* __restrict__ O) {
  int t = blockIdx.x * 256 + threadIdx.x;  // 1M threads
  int d = t & 1023, n = t >> 10;
  int h = n >> 6, dk = n & 63;
  float x = W[((size_t)(h << 10) + d) * 64 + dk];
  unsigned short hi, lo;
  split2(x, hi, lo);
  size_t ro = (size_t)n * GKB + d;
  O[ro] = hi;
  O[ro + 1024] = hi;
  O[ro + 2048] = lo;
}

// ---------------------------------------------------------------------------
// split_wo: W fp32 [1024][1024] (row=out, col=in; already B^T) -> [1024][3072]
// ---------------------------------------------------------------------------
__global__ __launch_bounds__(256) void split_wo_kernel(const float* __restrict__ W,
                                                       unsigned short* __restrict__ O) {
  int t = blockIdx.x * 256 + threadIdx.x;  // 256K threads, 4 elems each
  int idx = t * 4;
  int n = idx >> 10, d = idx & 1023;
  float4 x = *(const float4*)&W[idx];
  union { unsigned short h[4]; ushort4 u; } uh, ul;
  split2(x.x, uh.h[0], ul.h[0]);
  split2(x.y, uh.h[1], ul.h[1]);
  split2(x.z, uh.h[2], ul.h[2]);
  split2(x.w, uh.h[3], ul.h[3]);
  size_t ro = (size_t)n * GKB + d;
  *(ushort4*)&O[ro] = uh.u;
  *(ushort4*)&O[ro + 1024] = uh.u;
  *(ushort4*)&O[ro + 2048] = ul.u;
}

// ---------------------------------------------------------------------------
// gemm_bt_bf16: C[M x N] = A' @ BT'^T + bias over logical K=3072.
// Markidis 3-term: hi*hi + lo*hi + hi*lo (only lo*lo dropped).
// OUT=0: fp32 C.  OUT=1: split bf16 C [M][2048].
// ---------------------------------------------------------------------------
#define BK 32
template <int OUT>
__global__ __launch_bounds__(256) void gemm_bt_bf16(
    const unsigned short* __restrict__ A, const unsigned short* __restrict__ BT,
    const float* __restrict__ bias, float* __restrict__ Cf,
    unsigned short* __restrict__ Cs, int N) {
  __shared__ __align__(16) unsigned short As[128 * BK];
  __shared__ __align__(16) unsigned short Bs[128 * BK];
  const int tid = threadIdx.x;
  const int lane = tid & 63;
  const int w = tid >> 6;
  const int wm = (w >> 1) * 64;
  const int wn = (w & 1) * 64;
  const size_t bm = (size_t)blockIdx.y * 128;
  const size_t bn = (size_t)blockIdx.x * 128;

  f32x4 acc[4][4];
#pragma unroll
  for (int i = 0; i < 4; i++)
#pragma unroll
    for (int j = 0; j < 4; j++) acc[i][j] = (f32x4){0.f, 0.f, 0.f, 0.f};

  const int srow = lane >> 2;       // 0..15
  const int skof = (lane & 3) * 8;  // k elem offset
  const unsigned short* Ag0 = A + (bm + w * 32 + srow) * GKA + skof;
  const unsigned short* Ag1 = Ag0 + (size_t)16 * GKA;
  const unsigned short* Bg0 = BT + (bn + w * 32 + srow) * GKB + skof;
  const unsigned short* Bg1 = Bg0 + (size_t)16 * GKB;
  unsigned short* As0 = As + (w * 2) * 512;
  unsigned short* As1 = As0 + 512;
  unsigned short* Bs0 = Bs + (w * 2) * 512;
  unsigned short* Bs1 = Bs0 + 512;

  const int fm = lane & 15;
  const int fk = (lane >> 4) * 8;

  for (int k0 = 0; k0 < GKB; k0 += BK) {
    const int ak = (k0 < 2048) ? k0 : (k0 - 2048);  // third block re-reads hi
    __syncthreads();
    __builtin_amdgcn_global_load_lds((const __attribute__((address_space(1))) void*)(Ag0 + ak),
                                     (__attribute__((address_space(3))) void*)As0, 16, 0, 0);
    __builtin_amdgcn_global_load_lds((const __attribute__((address_space(1))) void*)(Ag1 + ak),
                                     (__attribute__((address_space(3))) void*)As1, 16, 0, 0);
    __builtin_amdgcn_global_load_lds((const __attribute__((address_space(1))) void*)(Bg0 + k0),
                                     (__attribute__((address_space(3))) void*)Bs0, 16, 0, 0);
    __builtin_amdgcn_global_load_lds((const __attribute__((address_space(1))) void*)(Bg1 + k0),
                                     (__attribute__((address_space(3))) void*)Bs1, 16, 0, 0);
    __syncthreads();
    bf16x8 af[4], bf[4];
#pragma unroll
    for (int i = 0; i < 4; i++) {
      af[i] = *(const bf16x8*)&As[(wm + i * 16 + fm) * BK + fk];
      bf[i] = *(const bf16x8*)&Bs[(wn + i * 16 + fm) * BK + fk];
    }
#pragma unroll
    for (int i = 0; i < 4; i++)
#pragma unroll
      for (int j = 0; j < 4; j++)
        acc[i][j] = __builtin_amdgcn_mfma_f32_16x16x32_bf16(af[i], bf[j], acc[i][j], 0, 0, 0);
  }

  const int r0 = (lane >> 4) * 4;
#pragma unroll
  for (int i = 0; i < 4; i++)
#pragma unroll
    for (int j = 0; j < 4; j++) {
      size_t row = bm + wm + i * 16 + r0;
      size_t col = bn + wn + j * 16 + fm;
      float bb = bias[col];
#pragma unroll
      for (int r = 0; r < 4; r++) {
        float val = acc[i][j][r] + bb;
        if (OUT == 0) {
          Cf[(row + r) * N + col] = val;
        } else {
          unsigned short hi, lo;
          split2(val, hi, lo);
          Cs[(row + r) * GKA + col] = hi;
          Cs[(row + r) * GKA + 1024 + col] = lo;
        }
      }
    }
}

// ---------------------------------------------------------------------------
// M[b,h] = kh^T @ vh (64x64 per (b,h)), s-split 8-way with atomics.
// ---------------------------------------------------------------------------
__global__ __launch_bounds__(256) void compute_m_kernel(
    const float* __restrict__ KH, const float* __restrict__ VH, float* __restrict__ Mout) {
  const int sc = blockIdx.x, h = blockIdx.y, b = blockIdx.z;
  const int tid = threadIdx.x;
  const int i0 = (tid >> 4) * 4;
  const int j0 = (tid & 15) * 4;
  __shared__ float ks[16][64], vs[16][64];
  float acc[4][4];
#pragma unroll
  for (int a = 0; a < 4; a++)
#pragma unroll
    for (int c = 0; c < 4; c++) acc[a][c] = 0.f;

  const int s0 = sc * (S / 8);
  const int rr = tid >> 4;
  const int cc = (tid & 15) * 4;
  for (int s = s0; s < s0 + S / 8; s += 16) {
    size_t base = ((size_t)b * S + s + rr) * D + h * 64 + cc;
    __syncthreads();
    *(float4*)&ks[rr][cc] = *(const float4*)&KH[base];
    *(float4*)&vs[rr][cc] = *(const float4*)&VH[base];
    __syncthreads();
#pragma unroll
    for (int ss = 0; ss < 16; ss++) {
      float4 kf = *(const float4*)&ks[ss][i0];
      float4 vf = *(const float4*)&vs[ss][j0];
      float ka[4] = {kf.x, kf.y, kf.z, kf.w};
      float va[4] = {vf.x, vf.y, vf.z, vf.w};
#pragma unroll
      for (int a = 0; a < 4; a++)
#pragma unroll
        for (int c = 0; c < 4; c++) acc[a][c] += ka[a] * va[c];
    }
  }
  float* Mp = Mout + ((size_t)(b * H + h)) * DK * DK;
#pragma unroll
  for (int a = 0; a < 4; a++)
#pragma unroll
    for (int c = 0; c < 4; c++) atomicAdd(&Mp[(i0 + a) * DK + j0 + c], acc[a][c]);
}

// ---------------------------------------------------------------------------
// qm_mfma_softmax: heads = softmax_j( 0.125 * qh @ M[b,h] ) via 3-term split
// MFMA. QS [8192][2048] ([hi|lo]) read AND written in place (per-wave disjoint
// 16-row x 1-head windows). M split to bf16 hi/lo in LDS, stored transposed
// M_T[n][k] so B-fragments are single ds_read_b128.
// grid (S/64, H, B), 256 threads; wave w owns rows [sc*64+w*16, +16).
// ---------------------------------------------------------------------------
__global__ __launch_bounds__(256) void qm_mfma_softmax_kernel(
    unsigned short* __restrict__ QS, const float* __restrict__ Mmat) {
  const int sc = blockIdx.x, h = blockIdx.y, b = blockIdx.z;
  const int tid = threadIdx.x;
  const int lane = tid & 63;
  const int w = tid >> 6;

  __shared__ unsigned short MhiT[64][72];  // [n][k], pad 72 to spread banks
  __shared__ unsigned short MloT[64][72];
  {
    const float* Mp = Mmat + ((size_t)(b * H + h)) * 4096;
    for (int idx = tid; idx < 4096; idx += 256) {
      int kk = idx >> 6, nn = idx & 63;
      unsigned short hi, lo;
      split2(Mp[idx], hi, lo);
      MhiT[nn][kk] = hi;
      MloT[nn][kk] = lo;
    }
  }
  __syncthreads();

  const int fm = lane & 15;        // A row / C col within 16
  const int quad = lane >> 4;      // 0..3
  const int ko = quad * 8;

  // A fragments: row = rbase + fm, k contiguous 8 elements
  const size_t rbase = (size_t)b * S + sc * 64 + w * 16;
  const unsigned short* qrow = QS + (rbase + fm) * GKA + h * 64;
  bf16x8 ahi0 = *(const bf16x8*)&qrow[ko];
  bf16x8 ahi1 = *(const bf16x8*)&qrow[32 + ko];
  bf16x8 alo0 = *(const bf16x8*)&qrow[1024 + ko];
  bf16x8 alo1 = *(const bf16x8*)&qrow[1024 + 32 + ko];

  // B fragments: B[k][n] = M[k][n] -> read M_T[n][k..k+7]
  bf16x8 bhi[2][4], blo[2][4];
#pragma unroll
  for (int t = 0; t < 2; t++)
#pragma unroll
    for (int j = 0; j < 4; j++) {
      bhi[t][j] = *(const bf16x8*)&MhiT[j * 16 + fm][t * 32 + ko];
      blo[t][j] = *(const bf16x8*)&MloT[j * 16 + fm][t * 32 + ko];
    }

  f32x4 acc[4];
#pragma unroll
  for (int j = 0; j < 4; j++) acc[j] = (f32x4){0.f, 0.f, 0.f, 0.f};
#pragma unroll
  for (int j = 0; j < 4; j++) {
    acc[j] = __builtin_amdgcn_mfma_f32_16x16x32_bf16(ahi0, bhi[0][j], acc[j], 0, 0, 0);
    acc[j] = __builtin_amdgcn_mfma_f32_16x16x32_bf16(ahi1, bhi[1][j], acc[j], 0, 0, 0);
    acc[j] = __builtin_amdgcn_mfma_f32_16x16x32_bf16(alo0, bhi[0][j], acc[j], 0, 0, 0);
    acc[j] = __builtin_amdgcn_mfma_f32_16x16x32_bf16(alo1, bhi[1][j], acc[j], 0, 0, 0);
    acc[j] = __builtin_amdgcn_mfma_f32_16x16x32_bf16(ahi0, blo[0][j], acc[j], 0, 0, 0);
    acc[j] = __builtin_amdgcn_mfma_f32_16x16x32_bf16(ahi1, blo[1][j], acc[j], 0, 0, 0);
  }

  // scale -> per-row softmax. C layout: col = j*16 + fm, row = quad*4 + r.
  // Row r's 64 values live in lanes (quad fixed) x (fm 0..15) x (j 0..3), reg r.
  f32x4 l[4];
#pragma unroll
  for (int j = 0; j < 4; j++)
#pragma unroll
    for (int r = 0; r < 4; r++) l[j][r] = acc[j][r] * 0.125f;

  f32x4 mx = l[0];
#pragma unroll
  for (int j = 1; j < 4; j++)
#pragma unroll
    for (int r = 0; r < 4; r++) mx[r] = fmaxf(mx[r], l[j][r]);
#pragma unroll
  for (int off = 1; off < 16; off <<= 1)
#pragma unroll
    for (int r = 0; r < 4; r++) mx[r] = fmaxf(mx[r], __shfl_xor(mx[r], off, 64));

  f32x4 e[4];
  f32x4 sm = (f32x4){0.f, 0.f, 0.f, 0.f};
#pragma unroll
  for (int j = 0; j < 4; j++)
#pragma unroll
    for (int r = 0; r < 4; r++) {
      e[j][r] = __expf(l[j][r] - mx[r]);
      sm[r] += e[j][r];
    }
#pragma unroll
  for (int off = 1; off < 16; off <<= 1)
#pragma unroll
    for (int r = 0; r < 4; r++) sm[r] += __shfl_xor(sm[r], off, 64);

  f32x4 inv;
#pragma unroll
  for (int r = 0; r < 4; r++) inv[r] = 1.0f / sm[r];

#pragma unroll
  for (int j = 0; j < 4; j++)
#pragma unroll
    for (int r = 0; r < 4; r++) {
      float p = e[j][r] * inv[r];
      unsigned short hi, lo;
      split2(p, hi, lo);
      size_t ro = (rbase + quad * 4 + r) * GKA + h * 64 + j * 16 + fm;
      QS[ro] = hi;
      QS[ro + 1024] = lo;
    }
}

// ---------------------------------------------------------------------------
extern "C" void kernel_launch(void* const* d_in, const int* in_sizes, int n_in,
                              void* d_out, int out_size, void* d_ws, size_t ws_size,
                              hipStream_t stream) {
  const float* q = (const float*)d_in[0];
  const float* k = (const float*)d_in[1];
  const float* v = (const float*)d_in[2];
  const float* wq_w = (const float*)d_in[3];
  const float* wq_b = (const float*)d_in[4];
  const float* wk_w = (const float*)d_in[5];
  const float* wk_b = (const float*)d_in[6];
  const float* wv_w = (const float*)d_in[7];
  const float* wv_b = (const float*)d_in[8];
  const float* wo_w = (const float*)d_in[9];
  const float* wo_b = (const float*)d_in[10];
  float* out = (float*)d_out;

  // ws: KH 32MB (reused as QS) | VH 32MB | M 1MB | ASP 32MB | 4x W splits 6MB
  const size_t nProj = (size_t)MS * D;
  float* KH = (float*)d_ws;
  float* VH = KH + nProj;
  float* M = VH + nProj;
  unsigned short* ASP = (unsigned short*)(M + 256 * 1024);
  unsigned short* WQS = ASP + (size_t)MS * GKA;
  unsigned short* WKS = WQS + (size_t)D * GKB;
  unsigned short* WVS = WKS + (size_t)D * GKB;
  unsigned short* WOS = WVS + (size_t)D * GKB;
  unsigned short* QS = (unsigned short*)KH;  // aliases KH after compute_m

  dim3 blk(256);
  dim3 gemmGrid(D / 128, MS / 128);

  split_wp_kernel<<<4096, blk, 0, stream>>>(wq_w, WQS);
  split_wp_kernel<<<4096, blk, 0, stream>>>(wk_w, WKS);
  split_wp_kernel<<<4096, blk, 0, stream>>>(wv_w, WVS);
  split_wo_kernel<<<1024, blk, 0, stream>>>(wo_w, WOS);
  hipMemsetAsync(M, 0, (size_t)B * H * DK * DK * sizeof(float), stream);

  split_a_kernel<<<8192, blk, 0, stream>>>(k, ASP);
  gemm_bt_bf16<0><<<gemmGrid, blk, 0, stream>>>(ASP, WKS, wk_b, KH, nullptr, D);
  split_a_kernel<<<8192, blk, 0, stream>>>(v, ASP);
  gemm_bt_bf16<0><<<gemmGrid, blk, 0, stream>>>(ASP, WVS, wv_b, VH, nullptr, D);

  compute_m_kernel<<<dim3(8, H, B), blk, 0, stream>>>(KH, VH, M);

  split_a_kernel<<<8192, blk, 0, stream>>>(q, ASP);
  gemm_bt_bf16<1><<<gemmGrid, blk, 0, stream>>>(ASP, WQS, wq_b, nullptr, QS, D);

  qm_mfma_softmax_kernel<<<dim3(S / 64, H, B), blk, 0, stream>>>(QS, M);

  gemm_bt_bf16<0><<<gemmGrid, blk, 0, stream>>>(QS, WOS, wo_b, out, nullptr, D);
}

// Round 5
// 503.673 us; speedup vs baseline: 2.2633x; 1.0871x over previous
//
#include <hip/hip_runtime.h>
#include <math.h>

#define B 4
#define S 2048
#define D 1024
#define H 16
#define DK 64
#define MS (B * S)   // 8192
#define GKA 2048     // split storage width: [hi | lo]

typedef short bf16x8 __attribute__((ext_vector_type(8)));
typedef float f32x4 __attribute__((ext_vector_type(4)));

__device__ __forceinline__ unsigned short f2bf(float x) {
  union { float f; unsigned u; } v; v.f = x;
  unsigned r = v.u + 0x7fff + ((v.u >> 16) & 1);  // RNE
  return (unsigned short)(r >> 16);
}
__device__ __forceinline__ float bf2f(unsigned short h) {
  union { unsigned u; float f; } v; v.u = ((unsigned)h) << 16;
  return v.f;
}
__device__ __forceinline__ void split2(float x, unsigned short& hi, unsigned short& lo) {
  hi = f2bf(x);
  lo = f2bf(x - bf2f(hi));
}

// ---------------------------------------------------------------------------
// split_a: X fp32 [8192][1024] -> O bf16 [8192][2048] ([hi | lo]); z picks pair
// ---------------------------------------------------------------------------
__global__ __launch_bounds__(256) void split_a_kernel(
    const float* __restrict__ X0, const float* __restrict__ X1,
    unsigned short* __restrict__ O0, unsigned short* __restrict__ O1) {
  const float* X = blockIdx.z ? X1 : X0;
  unsigned short* O = blockIdx.z ? O1 : O0;
  int t = blockIdx.x * 256 + threadIdx.x;
  int idx = t * 4;
  int m = idx >> 10, d = idx & 1023;
  float4 x = *(const float4*)&X[idx];
  union { unsigned short h[4]; ushort4 u; } uh, ul;
  split2(x.x, uh.h[0], ul.h[0]);
  split2(x.y, uh.h[1], ul.h[1]);
  split2(x.z, uh.h[2], ul.h[2]);
  split2(x.w, uh.h[3], ul.h[3]);
  *(ushort4*)&O[(size_t)m * GKA + d] = uh.u;
  *(ushort4*)&O[(size_t)m * GKA + 1024 + d] = ul.u;
}

// ---------------------------------------------------------------------------
// split_wp: W fp32 [H][1024][64] -> O bf16 [1024][2048] ([hi|lo]), row n=h*64+dk
// z = 0,1,2 picks (Wq,Wk,Wv) -> (O0,O1,O2)
// ---------------------------------------------------------------------------
__global__ __launch_bounds__(256) void split_wp_kernel(
    const float* __restrict__ W0, const float* __restrict__ W1, const float* __restrict__ W2,
    unsigned short* __restrict__ O0, unsigned short* __restrict__ O1,
    unsigned short* __restrict__ O2) {
  const float* W = blockIdx.z == 0 ? W0 : (blockIdx.z == 1 ? W1 : W2);
  unsigned short* O = blockIdx.z == 0 ? O0 : (blockIdx.z == 1 ? O1 : O2);
  int t = blockIdx.x * 256 + threadIdx.x;  // 1M threads
  int d = t & 1023, n = t >> 10;
  int h = n >> 6, dk = n & 63;
  float x = W[((size_t)(h << 10) + d) * 64 + dk];
  unsigned short hi, lo;
  split2(x, hi, lo);
  size_t ro = (size_t)n * GKA + d;
  O[ro] = hi;
  O[ro + 1024] = lo;
}

// ---------------------------------------------------------------------------
// wo_cast: wo_w fp32 [1024][1024] (row=out, col=in; already B^T) -> plain bf16
// ---------------------------------------------------------------------------
__global__ __launch_bounds__(256) void wo_cast_kernel(const float* __restrict__ W,
                                                      unsigned short* __restrict__ O) {
  int t = blockIdx.x * 256 + threadIdx.x;  // 256K threads, 4 elems each
  int idx = t * 4;
  float4 x = *(const float4*)&W[idx];
  ushort4 u;
  u.x = f2bf(x.x); u.y = f2bf(x.y); u.z = f2bf(x.z); u.w = f2bf(x.w);
  *(ushort4*)&O[idx] = u;
}

// ---------------------------------------------------------------------------
// gemm_kernel: C[8192 x 1024] = A @ BT^T + bias, fp32 out.
// SPLIT=1: logical K=3072 Markidis 3-term (hi*hi + lo*hi + hi*lo);
//          A,BT stored [*][2048] = [hi|lo], wrap addressing.
// SPLIT=0: plain bf16, K=1024, A,BT stored [*][1024].
// 128x128 tile, BK=32, 4 waves, 16x16x32 MFMA, global_load_lds width 16.
// blockIdx.z picks (A,BT,bias,C) set 0 or 1.
// ---------------------------------------------------------------------------
#define BK 32
template <int SPLIT>
__global__ __launch_bounds__(256) void gemm_kernel(
    const unsigned short* __restrict__ A0, const unsigned short* __restrict__ A1,
    const unsigned short* __restrict__ B0, const unsigned short* __restrict__ B1,
    const float* __restrict__ bias0, const float* __restrict__ bias1,
    float* __restrict__ C0, float* __restrict__ C1) {
  const int KLOG = SPLIT ? 3072 : 1024;
  const int AST = SPLIT ? 2048 : 1024;
  const int BST = SPLIT ? 2048 : 1024;
  const unsigned short* A = blockIdx.z ? A1 : A0;
  const unsigned short* BT = blockIdx.z ? B1 : B0;
  const float* bias = blockIdx.z ? bias1 : bias0;
  float* C = blockIdx.z ? C1 : C0;

  __shared__ __align__(16) unsigned short As[128 * BK];
  __shared__ __align__(16) unsigned short Bs[128 * BK];
  const int tid = threadIdx.x;
  const int lane = tid & 63;
  const int w = tid >> 6;
  const int wm = (w >> 1) * 64;
  const int wn = (w & 1) * 64;
  const size_t bm = (size_t)blockIdx.y * 128;
  const size_t bn = (size_t)blockIdx.x * 128;

  f32x4 acc[4][4];
#pragma unroll
  for (int i = 0; i < 4; i++)
#pragma unroll
    for (int j = 0; j < 4; j++) acc[i][j] = (f32x4){0.f, 0.f, 0.f, 0.f};

  const int srow = lane >> 2;       // 0..15
  const int skof = (lane & 3) * 8;  // k elem offset
  const unsigned short* Ag0 = A + (bm + w * 32 + srow) * AST + skof;
  const unsigned short* Ag1 = Ag0 + (size_t)16 * AST;
  const unsigned short* Bg0 = BT + (bn + w * 32 + srow) * BST + skof;
  const unsigned short* Bg1 = Bg0 + (size_t)16 * BST;
  unsigned short* As0 = As + (w * 2) * 512;
  unsigned short* As1 = As0 + 512;
  unsigned short* Bs0 = Bs + (w * 2) * 512;
  unsigned short* Bs1 = Bs0 + 512;

  const int fm = lane & 15;
  const int fk = (lane >> 4) * 8;

  for (int k0 = 0; k0 < KLOG; k0 += BK) {
    const int aofs = SPLIT ? (k0 < 2048 ? k0 : k0 - 2048) : k0;  // A: [hi][lo][hi]
    const int bofs = SPLIT ? (k0 < 1024 ? k0 : k0 - 1024) : k0;  // B: [hi][hi][lo]
    __syncthreads();
    __builtin_amdgcn_global_load_lds((const __attribute__((address_space(1))) void*)(Ag0 + aofs),
                                     (__attribute__((address_space(3))) void*)As0, 16, 0, 0);
    __builtin_amdgcn_global_load_lds((const __attribute__((address_space(1))) void*)(Ag1 + aofs),
                                     (__attribute__((address_space(3))) void*)As1, 16, 0, 0);
    __builtin_amdgcn_global_load_lds((const __attribute__((address_space(1))) void*)(Bg0 + bofs),
                                     (__attribute__((address_space(3))) void*)Bs0, 16, 0, 0);
    __builtin_amdgcn_global_load_lds((const __attribute__((address_space(1))) void*)(Bg1 + bofs),
                                     (__attribute__((address_space(3))) void*)Bs1, 16, 0, 0);
    __syncthreads();
    bf16x8 af[4], bf[4];
#pragma unroll
    for (int i = 0; i < 4; i++) {
      af[i] = *(const bf16x8*)&As[(wm + i * 16 + fm) * BK + fk];
      bf[i] = *(const bf16x8*)&Bs[(wn + i * 16 + fm) * BK + fk];
    }
#pragma unroll
    for (int i = 0; i < 4; i++)
#pragma unroll
      for (int j = 0; j < 4; j++)
        acc[i][j] = __builtin_amdgcn_mfma_f32_16x16x32_bf16(af[i], bf[j], acc[i][j], 0, 0, 0);
  }

  const int r0 = (lane >> 4) * 4;
#pragma unroll
  for (int i = 0; i < 4; i++)
#pragma unroll
    for (int j = 0; j < 4; j++) {
      size_t row = bm + wm + i * 16 + r0;
      size_t col = bn + wn + j * 16 + fm;
      float bb = bias[col];
#pragma unroll
      for (int r = 0; r < 4; r++) C[(row + r) * D + col] = acc[i][j][r] + bb;
    }
}

// ---------------------------------------------------------------------------
// M[b,h] = kh^T @ vh (64x64 per (b,h)), s-split 8-way with atomics.
// ---------------------------------------------------------------------------
__global__ __launch_bounds__(256) void compute_m_kernel(
    const float* __restrict__ KH, const float* __restrict__ VH, float* __restrict__ Mout) {
  const int sc = blockIdx.x, h = blockIdx.y, b = blockIdx.z;
  const int tid = threadIdx.x;
  const int i0 = (tid >> 4) * 4;
  const int j0 = (tid & 15) * 4;
  __shared__ float ks[16][64], vs[16][64];
  float acc[4][4];
#pragma unroll
  for (int a = 0; a < 4; a++)
#pragma unroll
    for (int c = 0; c < 4; c++) acc[a][c] = 0.f;

  const int s0 = sc * (S / 8);
  const int rr = tid >> 4;
  const int cc = (tid & 15) * 4;
  for (int s = s0; s < s0 + S / 8; s += 16) {
    size_t base = ((size_t)b * S + s + rr) * D + h * 64 + cc;
    __syncthreads();
    *(float4*)&ks[rr][cc] = *(const float4*)&KH[base];
    *(float4*)&vs[rr][cc] = *(const float4*)&VH[base];
    __syncthreads();
#pragma unroll
    for (int ss = 0; ss < 16; ss++) {
      float4 kf = *(const float4*)&ks[ss][i0];
      float4 vf = *(const float4*)&vs[ss][j0];
      float ka[4] = {kf.x, kf.y, kf.z, kf.w};
      float va[4] = {vf.x, vf.y, vf.z, vf.w};
#pragma unroll
      for (int a = 0; a < 4; a++)
#pragma unroll
        for (int c = 0; c < 4; c++) acc[a][c] += ka[a] * va[c];
    }
  }
  float* Mp = Mout + ((size_t)(b * H + h)) * DK * DK;
#pragma unroll
  for (int a = 0; a < 4; a++)
#pragma unroll
    for (int c = 0; c < 4; c++) atomicAdd(&Mp[(i0 + a) * DK + j0 + c], acc[a][c]);
}

// ---------------------------------------------------------------------------
// split_m: M fp32 [bh][64k][64n] -> MSP bf16 [bh][2][64n][64k] (hi, lo; transposed)
// ---------------------------------------------------------------------------
__global__ __launch_bounds__(256) void split_m_kernel(const float* __restrict__ M,
                                                      unsigned short* __restrict__ MSP) {
  const int bh = blockIdx.x;
  const float* Mp = M + (size_t)bh * 4096;
  unsigned short* hiP = MSP + (size_t)bh * 8192;
  unsigned short* loP = hiP + 4096;
  for (int idx = threadIdx.x; idx < 4096; idx += 256) {
    int kk = idx >> 6, nn = idx & 63;
    unsigned short hi, lo;
    split2(Mp[idx], hi, lo);
    hiP[nn * 64 + kk] = hi;
    loP[nn * 64 + kk] = lo;
  }
}

// ---------------------------------------------------------------------------
// qm_mfma_softmax: heads = softmax_j( 0.125 * qh @ M[b,h] ), 3-term split MFMA.
// QH fp32 [8192][1024] (split to A-frags in registers); MSP bf16 B-frags direct
// from global (L2-hot); output plain bf16 HB [8192][1024]. No LDS, no syncs.
// grid (S/64, H, B), 256 threads; wave w owns rows [sc*64+w*16, +16).
// ---------------------------------------------------------------------------
__global__ __launch_bounds__(256) void qm_mfma_softmax_kernel(
    const float* __restrict__ QH, const unsigned short* __restrict__ MSP,
    unsigned short* __restrict__ HB) {
  const int sc = blockIdx.x, h = blockIdx.y, b = blockIdx.z;
  const int tid = threadIdx.x;
  const int lane = tid & 63;
  const int w = tid >> 6;

  const int fm = lane & 15;     // A row / C col within 16
  const int quad = lane >> 4;   // 0..3
  const int ko = quad * 8;

  // A fragments from fp32 QH, split in registers
  const size_t rbase = (size_t)b * S + sc * 64 + w * 16;
  const float* qrow = QH + (rbase + fm) * D + h * 64;
  float qf[16];
  *(float4*)&qf[0] = *(const float4*)&qrow[ko];
  *(float4*)&qf[4] = *(const float4*)&qrow[ko + 4];
  *(float4*)&qf[8] = *(const float4*)&qrow[32 + ko];
  *(float4*)&qf[12] = *(const float4*)&qrow[32 + ko + 4];
  bf16x8 ahi0, alo0, ahi1, alo1;
#pragma unroll
  for (int j = 0; j < 8; j++) {
    unsigned short hi, lo;
    split2(qf[j], hi, lo);
    ahi0[j] = (short)hi; alo0[j] = (short)lo;
    split2(qf[8 + j], hi, lo);
    ahi1[j] = (short)hi; alo1[j] = (short)lo;
  }

  // B fragments direct from global MSP (transposed layout [n][k])
  const unsigned short* hiP = MSP + ((size_t)(b * H + h)) * 8192;
  const unsigned short* loP = hiP + 4096;
  bf16x8 bhi[2][4], blo[2][4];
#pragma unroll
  for (int t = 0; t < 2; t++)
#pragma unroll
    for (int j = 0; j < 4; j++) {
      bhi[t][j] = *(const bf16x8*)&hiP[(j * 16 + fm) * 64 + t * 32 + ko];
      blo[t][j] = *(const bf16x8*)&loP[(j * 16 + fm) * 64 + t * 32 + ko];
    }

  f32x4 acc[4];
#pragma unroll
  for (int j = 0; j < 4; j++) acc[j] = (f32x4){0.f, 0.f, 0.f, 0.f};
#pragma unroll
  for (int j = 0; j < 4; j++) {
    acc[j] = __builtin_amdgcn_mfma_f32_16x16x32_bf16(ahi0, bhi[0][j], acc[j], 0, 0, 0);
    acc[j] = __builtin_amdgcn_mfma_f32_16x16x32_bf16(ahi1, bhi[1][j], acc[j], 0, 0, 0);
    acc[j] = __builtin_amdgcn_mfma_f32_16x16x32_bf16(alo0, bhi[0][j], acc[j], 0, 0, 0);
    acc[j] = __builtin_amdgcn_mfma_f32_16x16x32_bf16(alo1, bhi[1][j], acc[j], 0, 0, 0);
    acc[j] = __builtin_amdgcn_mfma_f32_16x16x32_bf16(ahi0, blo[0][j], acc[j], 0, 0, 0);
    acc[j] = __builtin_amdgcn_mfma_f32_16x16x32_bf16(ahi1, blo[1][j], acc[j], 0, 0, 0);
  }

  // scale -> per-row softmax. C layout: col = j*16+fm, row = quad*4+r.
  f32x4 l[4];
#pragma unroll
  for (int j = 0; j < 4; j++)
#pragma unroll
    for (int r = 0; r < 4; r++) l[j][r] = acc[j][r] * 0.125f;

  f32x4 mx = l[0];
#pragma unroll
  for (int j = 1; j < 4; j++)
#pragma unroll
    for (int r = 0; r < 4; r++) mx[r] = fmaxf(mx[r], l[j][r]);
#pragma unroll
  for (int off = 1; off < 16; off <<= 1)
#pragma unroll
    for (int r = 0; r < 4; r++) mx[r] = fmaxf(mx[r], __shfl_xor(mx[r], off, 64));

  f32x4 e[4];
  f32x4 sm = (f32x4){0.f, 0.f, 0.f, 0.f};
#pragma unroll
  for (int j = 0; j < 4; j++)
#pragma unroll
    for (int r = 0; r < 4; r++) {
      e[j][r] = __expf(l[j][r] - mx[r]);
      sm[r] += e[j][r];
    }
#pragma unroll
  for (int off = 1; off < 16; off <<= 1)
#pragma unroll
    for (int r = 0; r < 4; r++) sm[r] += __shfl_xor(sm[r], off, 64);

  f32x4 inv;
#pragma unroll
  for (int r = 0; r < 4; r++) inv[r] = 1.0f / sm[r];

#pragma unroll
  for (int j = 0; j < 4; j++)
#pragma unroll
    for (int r = 0; r < 4; r++) {
      float p = e[j][r] * inv[r];
      HB[(rbase + quad * 4 + r) * D + h * 64 + j * 16 + fm] = f2bf(p);
    }
}

// ---------------------------------------------------------------------------
extern "C" void kernel_launch(void* const* d_in, const int* in_sizes, int n_in,
                              void* d_out, int out_size, void* d_ws, size_t ws_size,
                              hipStream_t stream) {
  const float* q = (const float*)d_in[0];
  const float* k = (const float*)d_in[1];
  const float* v = (const float*)d_in[2];
  const float* wq_w = (const float*)d_in[3];
  const float* wq_b = (const float*)d_in[4];
  const float* wk_w = (const float*)d_in[5];
  const float* wk_b = (const float*)d_in[6];
  const float* wv_w = (const float*)d_in[7];
  const float* wv_b = (const float*)d_in[8];
  const float* wo_w = (const float*)d_in[9];
  const float* wo_b = (const float*)d_in[10];
  float* out = (float*)d_out;

  // ws layout (142 MB):
  // KH 32 | VH 32 (-> QH alias) | M 1 | MSP 1 | KSP 32 (-> HB 16 + WOB 2) |
  // VSP 32 | WQS 4 | WKS 4 | WVS 4
  const size_t nProj = (size_t)MS * D;  // 8M floats
  float* KH = (float*)d_ws;
  float* VH = KH + nProj;
  float* M = VH + nProj;                              // 256K floats
  unsigned short* MSP = (unsigned short*)(M + 256 * 1024);  // 512K ushorts
  unsigned short* KSP = MSP + 512 * 1024;             // 16M ushorts
  unsigned short* VSP = KSP + (size_t)16 * 1024 * 1024;
  unsigned short* WQS = VSP + (size_t)16 * 1024 * 1024;  // 2M ushorts each
  unsigned short* WKS = WQS + (size_t)2 * 1024 * 1024;
  unsigned short* WVS = WKS + (size_t)2 * 1024 * 1024;
  // aliases (after their sources are dead)
  float* QH = VH;                              // reuse VH? NO - VH needed for cM.
  QH = (float*)VSP;                            // VSP dead after gKV
  unsigned short* HB = KSP;                    // KSP dead after gQ
  unsigned short* WOB = KSP + (size_t)8 * 1024 * 1024;  // 1M ushorts, after HB

  dim3 blk(256);

  hipMemsetAsync(M, 0, (size_t)B * H * DK * DK * sizeof(float), stream);
  split_wp_kernel<<<dim3(4096, 1, 3), blk, 0, stream>>>(wq_w, wk_w, wv_w, WQS, WKS, WVS);
  split_a_kernel<<<dim3(8192, 1, 2), blk, 0, stream>>>(k, v, KSP, VSP);
  gemm_kernel<1><<<dim3(8, 64, 2), blk, 0, stream>>>(KSP, VSP, WKS, WVS, wk_b, wv_b, KH, VH);
  compute_m_kernel<<<dim3(8, H, B), blk, 0, stream>>>(KH, VH, M);
  split_m_kernel<<<64, blk, 0, stream>>>(M, MSP);
  split_a_kernel<<<dim3(8192, 1, 1), blk, 0, stream>>>(q, q, KSP, KSP);
  gemm_kernel<1><<<dim3(8, 64, 1), blk, 0, stream>>>(KSP, KSP, WQS, WQS, wq_b, wq_b, QH, QH);
  wo_cast_kernel<<<1024, blk, 0, stream>>>(wo_w, WOB);
  qm_mfma_softmax_kernel<<<dim3(S / 64, H, B), blk, 0, stream>>>(QH, MSP, HB);
  gemm_kernel<0><<<dim3(8, 64, 1), blk, 0, stream>>>(HB, HB, WOB, WOB, wo_b, wo_b, out, out);
}

// Round 7
// 480.194 us; speedup vs baseline: 2.3740x; 1.0489x over previous
//
#include <hip/hip_runtime.h>
#include <math.h>

#define B 4
#define S 2048
#define D 1024
#define H 16
#define DK 64
#define MS (B * S)   // 8192
#define GKA 2048     // split storage width: [hi | lo]

typedef short bf16x8 __attribute__((ext_vector_type(8)));
typedef float f32x4 __attribute__((ext_vector_type(4)));

__device__ __forceinline__ unsigned short f2bf(float x) {
  union { float f; unsigned u; } v; v.f = x;
  unsigned r = v.u + 0x7fff + ((v.u >> 16) & 1);  // RNE
  return (unsigned short)(r >> 16);
}
__device__ __forceinline__ float bf2f(unsigned short h) {
  union { unsigned u; float f; } v; v.u = ((unsigned)h) << 16;
  return v.f;
}
__device__ __forceinline__ void split2(float x, unsigned short& hi, unsigned short& lo) {
  hi = f2bf(x);
  lo = f2bf(x - bf2f(hi));
}

// ---------------------------------------------------------------------------
// prep: ALL input preprocessing in one launch, chunked by blockIdx.x:
//  [0,24576)      split k,v,q -> KSP,VSP,QSP  [8192][2048] ([hi|lo])
//  [24576,32768)  split wk,wv -> WKS,WVS      [1024][2048] (B^T layout)
//  [32768,36864)  split wq    -> WQA [16][1024][128] (A layout, [hi|lo] along k)
//  [36864,37888)  cast wo     -> WOB [1024][1024] plain bf16 (B^T layout)
//  [37888,38144)  zero M
// ---------------------------------------------------------------------------
__global__ __launch_bounds__(256) void prep_kernel(
    const float* __restrict__ q, const float* __restrict__ k, const float* __restrict__ v,
    const float* __restrict__ wk, const float* __restrict__ wv, const float* __restrict__ wq,
    const float* __restrict__ wo,
    unsigned short* __restrict__ KSP, unsigned short* __restrict__ VSP,
    unsigned short* __restrict__ QSP,
    unsigned short* __restrict__ WKS, unsigned short* __restrict__ WVS,
    unsigned short* __restrict__ WQA, unsigned short* __restrict__ WOB,
    float* __restrict__ M) {
  const int blk = blockIdx.x;
  const int tid = threadIdx.x;
  if (blk < 24576) {  // activation splits
    const int which = blk >> 13;
    const int bb = blk & 8191;
    const float* X = which == 0 ? k : (which == 1 ? v : q);
    unsigned short* O = which == 0 ? KSP : (which == 1 ? VSP : QSP);
    int t = bb * 256 + tid;
    int idx = t * 4;
    int m = idx >> 10, d = idx & 1023;
    float4 x = *(const float4*)&X[idx];
    union { unsigned short h[4]; ushort4 u; } uh, ul;
    split2(x.x, uh.h[0], ul.h[0]);
    split2(x.y, uh.h[1], ul.h[1]);
    split2(x.z, uh.h[2], ul.h[2]);
    split2(x.w, uh.h[3], ul.h[3]);
    *(ushort4*)&O[(size_t)m * GKA + d] = uh.u;
    *(ushort4*)&O[(size_t)m * GKA + 1024 + d] = ul.u;
  } else if (blk < 32768) {  // wk/wv splits (B^T layout)
    const int which = (blk - 24576) >> 12;
    const int bb = (blk - 24576) & 4095;
    const float* W = which == 0 ? wk : wv;
    unsigned short* O = which == 0 ? WKS : WVS;
    int t = bb * 256 + tid;
    int d = t & 1023, n = t >> 10;
    int h = n >> 6, dk = n & 63;
    float x = W[((size_t)(h << 10) + d) * 64 + dk];
    unsigned short hi, lo;
    split2(x, hi, lo);
    size_t ro = (size_t)n * GKA + d;
    O[ro] = hi;
    O[ro + 1024] = lo;
  } else if (blk < 36864) {  // wq split (A layout: [h][d][hi 64|lo 64])
    int t = (blk - 32768) * 256 + tid;  // 1M = 16*1024*64
    int kk = t & 63;
    int hd = t >> 6;  // h*1024 + d
    float x = wq[t];
    unsigned short hi, lo;
    split2(x, hi, lo);
    WQA[(size_t)hd * 128 + kk] = hi;
    WQA[(size_t)hd * 128 + 64 + kk] = lo;
  } else if (blk < 37888) {  // wo cast
    int t = (blk - 36864) * 256 + tid;
    int idx = t * 4;
    float4 x = *(const float4*)&wo[idx];
    ushort4 u;
    u.x = f2bf(x.x); u.y = f2bf(x.y); u.z = f2bf(x.z); u.w = f2bf(x.w);
    *(ushort4*)&WOB[idx] = u;
  } else {  // zero M (256 blocks * 256 threads * 4 = 262144 floats)
    int t = (blk - 37888) * 256 + tid;
    *(float4*)&M[(size_t)t * 4] = (float4){0.f, 0.f, 0.f, 0.f};
  }
}

// ---------------------------------------------------------------------------
// gemm_kernel: C[8192 x 1024] = A @ BT^T + bias, fp32 out.
// SPLIT=1: logical K=3072 Markidis 3-term; A,BT [*][2048]=[hi|lo], wrap addr.
// SPLIT=0: plain bf16, K=1024.
// ---------------------------------------------------------------------------
#define BK 32
template <int SPLIT>
__global__ __launch_bounds__(256) void gemm_kernel(
    const unsigned short* __restrict__ A0, const unsigned short* __restrict__ A1,
    const unsigned short* __restrict__ B0, const unsigned short* __restrict__ B1,
    const float* __restrict__ bias0, const float* __restrict__ bias1,
    float* __restrict__ C0, float* __restrict__ C1) {
  const int KLOG = SPLIT ? 3072 : 1024;
  const int AST = SPLIT ? 2048 : 1024;
  const int BST = SPLIT ? 2048 : 1024;
  const unsigned short* A = blockIdx.z ? A1 : A0;
  const unsigned short* BT = blockIdx.z ? B1 : B0;
  const float* bias = blockIdx.z ? bias1 : bias0;
  float* C = blockIdx.z ? C1 : C0;

  __shared__ __align__(16) unsigned short As[128 * BK];
  __shared__ __align__(16) unsigned short Bs[128 * BK];
  const int tid = threadIdx.x;
  const int lane = tid & 63;
  const int w = tid >> 6;
  const int wm = (w >> 1) * 64;
  const int wn = (w & 1) * 64;
  const size_t bm = (size_t)blockIdx.y * 128;
  const size_t bn = (size_t)blockIdx.x * 128;

  f32x4 acc[4][4];
#pragma unroll
  for (int i = 0; i < 4; i++)
#pragma unroll
    for (int j = 0; j < 4; j++) acc[i][j] = (f32x4){0.f, 0.f, 0.f, 0.f};

  const int srow = lane >> 2;
  const int skof = (lane & 3) * 8;
  const unsigned short* Ag0 = A + (bm + w * 32 + srow) * AST + skof;
  const unsigned short* Ag1 = Ag0 + (size_t)16 * AST;
  const unsigned short* Bg0 = BT + (bn + w * 32 + srow) * BST + skof;
  const unsigned short* Bg1 = Bg0 + (size_t)16 * BST;
  unsigned short* As0 = As + (w * 2) * 512;
  unsigned short* As1 = As0 + 512;
  unsigned short* Bs0 = Bs + (w * 2) * 512;
  unsigned short* Bs1 = Bs0 + 512;

  const int fm = lane & 15;
  const int fk = (lane >> 4) * 8;

  for (int k0 = 0; k0 < KLOG; k0 += BK) {
    const int aofs = SPLIT ? (k0 < 2048 ? k0 : k0 - 2048) : k0;
    const int bofs = SPLIT ? (k0 < 1024 ? k0 : k0 - 1024) : k0;
    __syncthreads();
    __builtin_amdgcn_global_load_lds((const __attribute__((address_space(1))) void*)(Ag0 + aofs),
                                     (__attribute__((address_space(3))) void*)As0, 16, 0, 0);
    __builtin_amdgcn_global_load_lds((const __attribute__((address_space(1))) void*)(Ag1 + aofs),
                                     (__attribute__((address_space(3))) void*)As1, 16, 0, 0);
    __builtin_amdgcn_global_load_lds((const __attribute__((address_space(1))) void*)(Bg0 + bofs),
                                     (__attribute__((address_space(3))) void*)Bs0, 16, 0, 0);
    __builtin_amdgcn_global_load_lds((const __attribute__((address_space(1))) void*)(Bg1 + bofs),
                                     (__attribute__((address_space(3))) void*)Bs1, 16, 0, 0);
    __syncthreads();
    bf16x8 af[4], bf[4];
#pragma unroll
    for (int i = 0; i < 4; i++) {
      af[i] = *(const bf16x8*)&As[(wm + i * 16 + fm) * BK + fk];
      bf[i] = *(const bf16x8*)&Bs[(wn + i * 16 + fm) * BK + fk];
    }
#pragma unroll
    for (int i = 0; i < 4; i++)
#pragma unroll
      for (int j = 0; j < 4; j++)
        acc[i][j] = __builtin_amdgcn_mfma_f32_16x16x32_bf16(af[i], bf[j], acc[i][j], 0, 0, 0);
  }

  const int r0 = (lane >> 4) * 4;
#pragma unroll
  for (int i = 0; i < 4; i++)
#pragma unroll
    for (int j = 0; j < 4; j++) {
      size_t row = bm + wm + i * 16 + r0;
      size_t col = bn + wn + j * 16 + fm;
      float bb = bias[col];
#pragma unroll
      for (int r = 0; r < 4; r++) C[(row + r) * D + col] = acc[i][j][r] + bb;
    }
}

// ---------------------------------------------------------------------------
// gemm_q_softmax: fused logit GEMM + softmax epilogue.
// logits = (QSP @ WQM[b]^T + BQM[b]) * 0.125; heads = softmax per head-row.
// A = QSP [8192][2048] split; B = WQM[b] [1024][2048] split (Wq' = Wq*M[b,h]);
// bias BQM [4][1024] (bq*M). Output HB plain bf16 [8192][1024].
// Each wave's 64 cols = exactly one head; rows complete in-wave.
// ---------------------------------------------------------------------------
__global__ __launch_bounds__(256) void gemm_q_softmax(
    const unsigned short* __restrict__ A, const unsigned short* __restrict__ WQM,
    const float* __restrict__ BQM, unsigned short* __restrict__ HB) {
  const int b = blockIdx.y >> 4;
  const unsigned short* BT = WQM + (size_t)b * D * GKA;

  __shared__ __align__(16) unsigned short As[128 * BK];
  __shared__ __align__(16) unsigned short Bs[128 * BK];
  const int tid = threadIdx.x;
  const int lane = tid & 63;
  const int w = tid >> 6;
  const int wm = (w >> 1) * 64;
  const int wn = (w & 1) * 64;
  const size_t bm = (size_t)blockIdx.y * 128;
  const size_t bn = (size_t)blockIdx.x * 128;

  f32x4 acc[4][4];
#pragma unroll
  for (int i = 0; i < 4; i++)
#pragma unroll
    for (int j = 0; j < 4; j++) acc[i][j] = (f32x4){0.f, 0.f, 0.f, 0.f};

  const int srow = lane >> 2;
  const int skof = (lane & 3) * 8;
  const unsigned short* Ag0 = A + (bm + w * 32 + srow) * GKA + skof;
  const unsigned short* Ag1 = Ag0 + (size_t)16 * GKA;
  const unsigned short* Bg0 = BT + (bn + w * 32 + srow) * GKA + skof;
  const unsigned short* Bg1 = Bg0 + (size_t)16 * GKA;
  unsigned short* As0 = As + (w * 2) * 512;
  unsigned short* As1 = As0 + 512;
  unsigned short* Bs0 = Bs + (w * 2) * 512;
  unsigned short* Bs1 = Bs0 + 512;

  const int fm = lane & 15;
  const int fk = (lane >> 4) * 8;

  for (int k0 = 0; k0 < 3072; k0 += BK) {
    const int aofs = (k0 < 2048) ? k0 : k0 - 2048;  // [hi][lo][hi]
    const int bofs = (k0 < 1024) ? k0 : k0 - 1024;  // [hi][hi][lo]
    __syncthreads();
    __builtin_amdgcn_global_load_lds((const __attribute__((address_space(1))) void*)(Ag0 + aofs),
                                     (__attribute__((address_space(3))) void*)As0, 16, 0, 0);
    __builtin_amdgcn_global_load_lds((const __attribute__((address_space(1))) void*)(Ag1 + aofs),
                                     (__attribute__((address_space(3))) void*)As1, 16, 0, 0);
    __builtin_amdgcn_global_load_lds((const __attribute__((address_space(1))) void*)(Bg0 + bofs),
                                     (__attribute__((address_space(3))) void*)Bs0, 16, 0, 0);
    __builtin_amdgcn_global_load_lds((const __attribute__((address_space(1))) void*)(Bg1 + bofs),
                                     (__attribute__((address_space(3))) void*)Bs1, 16, 0, 0);
    __syncthreads();
    bf16x8 af[4], bf[4];
#pragma unroll
    for (int i = 0; i < 4; i++) {
      af[i] = *(const bf16x8*)&As[(wm + i * 16 + fm) * BK + fk];
      bf[i] = *(const bf16x8*)&Bs[(wn + i * 16 + fm) * BK + fk];
    }
#pragma unroll
    for (int i = 0; i < 4; i++)
#pragma unroll
      for (int j = 0; j < 4; j++)
        acc[i][j] = __builtin_amdgcn_mfma_f32_16x16x32_bf16(af[i], bf[j], acc[i][j], 0, 0, 0);
  }

  // epilogue: this wave's 64 cols (head_col0..+63) are one full head
  const int quad = lane >> 4;
  const size_t head_col0 = bn + wn;
  float bj[4];
#pragma unroll
  for (int j = 0; j < 4; j++) bj[j] = BQM[(size_t)b * D + head_col0 + j * 16 + fm];

#pragma unroll
  for (int i = 0; i < 4; i++) {
    f32x4 val[4];
#pragma unroll
    for (int j = 0; j < 4; j++)
#pragma unroll
      for (int r = 0; r < 4; r++) val[j][r] = (acc[i][j][r] + bj[j]) * 0.125f;

    f32x4 mx = val[0];
#pragma unroll
    for (int j = 1; j < 4; j++)
#pragma unroll
      for (int r = 0; r < 4; r++) mx[r] = fmaxf(mx[r], val[j][r]);
#pragma unroll
    for (int off = 1; off < 16; off <<= 1)
#pragma unroll
      for (int r = 0; r < 4; r++) mx[r] = fmaxf(mx[r], __shfl_xor(mx[r], off, 64));

    f32x4 e[4];
    f32x4 sm = (f32x4){0.f, 0.f, 0.f, 0.f};
#pragma unroll
    for (int j = 0; j < 4; j++)
#pragma unroll
      for (int r = 0; r < 4; r++) {
        e[j][r] = __expf(val[j][r] - mx[r]);
        sm[r] += e[j][r];
      }
#pragma unroll
    for (int off = 1; off < 16; off <<= 1)
#pragma unroll
      for (int r = 0; r < 4; r++) sm[r] += __shfl_xor(sm[r], off, 64);

    f32x4 inv;
#pragma unroll
    for (int r = 0; r < 4; r++) inv[r] = 1.0f / sm[r];

#pragma unroll
    for (int j = 0; j < 4; j++)
#pragma unroll
      for (int r = 0; r < 4; r++) {
        size_t row = bm + wm + i * 16 + quad * 4 + r;
        HB[row * D + head_col0 + j * 16 + fm] = f2bf(e[j][r] * inv[r]);
      }
  }
}

// ---------------------------------------------------------------------------
// M[b,h] = kh^T @ vh (64x64 per (b,h)), s-split 8-way with atomics.
// ---------------------------------------------------------------------------
__global__ __launch_bounds__(256) void compute_m_kernel(
    const float* __restrict__ KH, const float* __restrict__ VH, float* __restrict__ Mout) {
  const int sc = blockIdx.x, h = blockIdx.y, b = blockIdx.z;
  const int tid = threadIdx.x;
  const int i0 = (tid >> 4) * 4;
  const int j0 = (tid & 15) * 4;
  __shared__ float ks[16][64], vs[16][64];
  float acc[4][4];
#pragma unroll
  for (int a = 0; a < 4; a++)
#pragma unroll
    for (int c = 0; c < 4; c++) acc[a][c] = 0.f;

  const int s0 = sc * (S / 8);
  const int rr = tid >> 4;
  const int cc = (tid & 15) * 4;
  for (int s = s0; s < s0 + S / 8; s += 16) {
    size_t base = ((size_t)b * S + s + rr) * D + h * 64 + cc;
    __syncthreads();
    *(float4*)&ks[rr][cc] = *(const float4*)&KH[base];
    *(float4*)&vs[rr][cc] = *(const float4*)&VH[base];
    __syncthreads();
#pragma unroll
    for (int ss = 0; ss < 16; ss++) {
      float4 kf = *(const float4*)&ks[ss][i0];
      float4 vf = *(const float4*)&vs[ss][j0];
      float ka[4] = {kf.x, kf.y, kf.z, kf.w};
      float va[4] = {vf.x, vf.y, vf.z, vf.w};
#pragma unroll
      for (int a = 0; a < 4; a++)
#pragma unroll
        for (int c = 0; c < 4; c++) acc[a][c] += ka[a] * va[c];
    }
  }
  float* Mp = Mout + ((size_t)(b * H + h)) * DK * DK;
#pragma unroll
  for (int a = 0; a < 4; a++)
#pragma unroll
    for (int c = 0; c < 4; c++) atomicAdd(&Mp[(i0 + a) * DK + j0 + c], acc[a][c]);
}

// ---------------------------------------------------------------------------
// split_m_bias: M fp32 [bh][64k][64n] -> MSP bf16 [bh][2][64n][64k] (transposed
// hi,lo) AND BQM[bh][64 j] = sum_k bq[h,k]*M[k,j]  (unscaled).
// ---------------------------------------------------------------------------
__global__ __launch_bounds__(256) void split_m_bias_kernel(
    const float* __restrict__ M, const float* __restrict__ bq,
    unsigned short* __restrict__ MSP, float* __restrict__ BQM) {
  const int bh = blockIdx.x;
  const int h = bh & 15;
  const float* Mp = M + (size_t)bh * 4096;
  unsigned short* hiP = MSP + (size_t)bh * 8192;
  unsigned short* loP = hiP + 4096;
  for (int idx = threadIdx.x; idx < 4096; idx += 256) {
    int kk = idx >> 6, nn = idx & 63;
    unsigned short hi, lo;
    split2(Mp[idx], hi, lo);
    hiP[nn * 64 + kk] = hi;
    loP[nn * 64 + kk] = lo;
  }
  if (threadIdx.x < 64) {
    int j = threadIdx.x;
    float a = 0.f;
#pragma unroll 8
    for (int kk = 0; kk < 64; kk++) a += bq[h * 64 + kk] * Mp[kk * 64 + j];
    BQM[(size_t)bh * 64 + j] = a;
  }
}

// ---------------------------------------------------------------------------
// wqm: Wq'[b,h] = Wq[h] @ M[b,h]  (1024x64 per pair), 3-term split MFMA.
// A = WQA [h][1024 d][hi64|lo64]; B = MSP [bh][2][64 n][64 k] (transposed).
// Output WQM [b][n=h*64+j][d hi | 1024+d lo] (B^T layout for gemm_q_softmax).
// grid (16, H, B); block = 64 d-rows; wave w owns d-rows [c*64+w*16, +16).
// ---------------------------------------------------------------------------
__global__ __launch_bounds__(256) void wqm_kernel(
    const unsigned short* __restrict__ WQA, const unsigned short* __restrict__ MSP,
    unsigned short* __restrict__ WQM) {
  const int c = blockIdx.x, h = blockIdx.y, b = blockIdx.z;
  const int tid = threadIdx.x;
  const int lane = tid & 63;
  const int w = tid >> 6;
  const int fm = lane & 15;
  const int quad = lane >> 4;
  const int ko = quad * 8;
  const int dbase = c * 64 + w * 16;

  const unsigned short* arow = WQA + ((size_t)h * 1024 + dbase + fm) * 128;
  bf16x8 ahi0 = *(const bf16x8*)&arow[ko];        // k 0..31 hi
  bf16x8 ahi1 = *(const bf16x8*)&arow[32 + ko];   // k 32..63 hi
  bf16x8 alo0 = *(const bf16x8*)&arow[64 + ko];   // k 0..31 lo
  bf16x8 alo1 = *(const bf16x8*)&arow[96 + ko];   // k 32..63 lo

  const unsigned short* hiP = MSP + ((size_t)(b * H + h)) * 8192;
  const unsigned short* loP = hiP + 4096;
  f32x4 acc[4];
#pragma unroll
  for (int j = 0; j < 4; j++) acc[j] = (f32x4){0.f, 0.f, 0.f, 0.f};
#pragma unroll
  for (int j = 0; j < 4; j++) {
    bf16x8 bhi0 = *(const bf16x8*)&hiP[(j * 16 + fm) * 64 + ko];
    bf16x8 bhi1 = *(const bf16x8*)&hiP[(j * 16 + fm) * 64 + 32 + ko];
    bf16x8 blo0 = *(const bf16x8*)&loP[(j * 16 + fm) * 64 + ko];
    bf16x8 blo1 = *(const bf16x8*)&loP[(j * 16 + fm) * 64 + 32 + ko];
    acc[j] = __builtin_amdgcn_mfma_f32_16x16x32_bf16(ahi0, bhi0, acc[j], 0, 0, 0);
    acc[j] = __builtin_amdgcn_mfma_f32_16x16x32_bf16(ahi1, bhi1, acc[j], 0, 0, 0);
    acc[j] = __builtin_amdgcn_mfma_f32_16x16x32_bf16(alo0, bhi0, acc[j], 0, 0, 0);
    acc[j] = __builtin_amdgcn_mfma_f32_16x16x32_bf16(alo1, bhi1, acc[j], 0, 0, 0);
    acc[j] = __builtin_amdgcn_mfma_f32_16x16x32_bf16(ahi0, blo0, acc[j], 0, 0, 0);
    acc[j] = __builtin_amdgcn_mfma_f32_16x16x32_bf16(ahi1, blo1, acc[j], 0, 0, 0);
  }

  // C[d=dbase+quad*4+r][col j*16+fm]; write split to WQM[b][h*64+col][d]
#pragma unroll
  for (int j = 0; j < 4; j++) {
    int n = h * 64 + j * 16 + fm;
    ushort4 hv, lv;
    unsigned short hi, lo;
    split2(acc[j][0], hi, lo); hv.x = hi; lv.x = lo;
    split2(acc[j][1], hi, lo); hv.y = hi; lv.y = lo;
    split2(acc[j][2], hi, lo); hv.z = hi; lv.z = lo;
    split2(acc[j][3], hi, lo); hv.w = hi; lv.w = lo;
    size_t base = ((size_t)b * D + n) * GKA + dbase + quad * 4;
    *(ushort4*)&WQM[base] = hv;
    *(ushort4*)&WQM[base + 1024] = lv;
  }
}

// ---------------------------------------------------------------------------
extern "C" void kernel_launch(void* const* d_in, const int* in_sizes, int n_in,
                              void* d_out, int out_size, void* d_ws, size_t ws_size,
                              hipStream_t stream) {
  const float* q = (const float*)d_in[0];
  const float* k = (const float*)d_in[1];
  const float* v = (const float*)d_in[2];
  const float* wq_w = (const float*)d_in[3];
  const float* wq_b = (const float*)d_in[4];
  const float* wk_w = (const float*)d_in[5];
  const float* wk_b = (const float*)d_in[6];
  const float* wv_w = (const float*)d_in[7];
  const float* wv_b = (const float*)d_in[8];
  const float* wo_w = (const float*)d_in[9];
  const float* wo_b = (const float*)d_in[10];
  float* out = (float*)d_out;

  // ws (143 MB): KSP 32 (->HB 16 | WQM 16) | VSP 32 (->MSP 1 + BQM) | QSP 32 |
  //              VH 32 | M 1 | WKS 4 | WVS 4 | WQA 4 | WOB 2.   KH lives in d_out.
  unsigned short* KSP = (unsigned short*)d_ws;
  unsigned short* VSP = KSP + (size_t)16 * 1024 * 1024;
  unsigned short* QSP = VSP + (size_t)16 * 1024 * 1024;
  float* VH = (float*)(QSP + (size_t)16 * 1024 * 1024);
  float* M = VH + (size_t)MS * D;
  unsigned short* WKS = (unsigned short*)(M + 256 * 1024);
  unsigned short* WVS = WKS + (size_t)2 * 1024 * 1024;
  unsigned short* WQA = WVS + (size_t)2 * 1024 * 1024;
  unsigned short* WOB = WQA + (size_t)2 * 1024 * 1024;
  // aliases
  float* KH = out;                                   // dead after compute_m
  unsigned short* HB = KSP;                          // KSP dead after gemm KV
  unsigned short* WQM = KSP + (size_t)8 * 1024 * 1024;
  unsigned short* MSP = VSP;                         // VSP dead after gemm KV
  float* BQM = (float*)(VSP + 512 * 1024);

  dim3 blk(256);

  prep_kernel<<<38144, blk, 0, stream>>>(q, k, v, wk_w, wv_w, wq_w, wo_w,
                                         KSP, VSP, QSP, WKS, WVS, WQA, WOB, M);
  gemm_kernel<1><<<dim3(8, 64, 2), blk, 0, stream>>>(KSP, VSP, WKS, WVS, wk_b, wv_b, KH, VH);
  compute_m_kernel<<<dim3(8, H, B), blk, 0, stream>>>(KH, VH, M);
  split_m_bias_kernel<<<64, blk, 0, stream>>>(M, wq_b, MSP, BQM);
  wqm_kernel<<<dim3(16, H, B), blk, 0, stream>>>(WQA, MSP, WQM);
  gemm_q_softmax<<<dim3(8, 64), blk, 0, stream>>>(QSP, WQM, BQM, HB);
  gemm_kernel<0><<<dim3(8, 64, 1), blk, 0, stream>>>(HB, HB, WOB, WOB, wo_b, wo_b, out, out);
}